// Round 2
// baseline (3087.146 us; speedup 1.0000x reference)
//
#include <hip/hip_runtime.h>
#include <math.h>

typedef __attribute__((ext_vector_type(8))) short short8;
typedef __attribute__((ext_vector_type(4))) float f32x4;
typedef unsigned short u16;

#define NTOK 841
#define GRID_H 29
#define E_ 384
#define NH_ 6
#define MROWS 13456
#define MP 13568
#define CM 2048

__device__ __forceinline__ u16 f2bf(float f) {
  union { float f; unsigned int u; } c; c.f = f;
  unsigned int u = c.u;
  return (u16)((u + 0x7fffu + ((u >> 16) & 1u)) >> 16);
}

__device__ __forceinline__ float gelu_exact(float v) {
  return 0.5f * v * (1.f + erff(v * 0.70710678118654752440f));
}

// ---------------- transpose + fp32->bf16 convert: in [K][N] -> out [N][K] ----
__global__ __launch_bounds__(256) void transpose_conv(const float* __restrict__ in,
    u16* __restrict__ out, int K, int N) {
  __shared__ float tile[32][33];
  size_t zo = (size_t)blockIdx.z * K * N;
  const float* inp = in + zo;
  u16* outp = out + zo;
  int n0 = blockIdx.x * 32, k0 = blockIdx.y * 32;
  int tx = threadIdx.x & 31, ty = threadIdx.x >> 5;
  #pragma unroll
  for (int r = ty; r < 32; r += 8) tile[r][tx] = inp[(size_t)(k0 + r) * N + n0 + tx];
  __syncthreads();
  #pragma unroll
  for (int r = ty; r < 32; r += 8) outp[(size_t)(n0 + r) * K + k0 + tx] = f2bf(tile[tx][r]);
}

// ---------------- fused 5-shift patchify + LayerNorm(3840) -> bf16 ----------
// writes rows [t0, t0+gridDim.x) of the virtual [MP,3840] matrix into
// out[blockIdx.x * 3840] (chunk-local).
__global__ __launch_bounds__(256) void patch_ln(const float* __restrict__ x,
    const float* __restrict__ g, const float* __restrict__ bsh, u16* __restrict__ out,
    int t0) {
  int t = t0 + blockIdx.x;
  int tid = threadIdx.x;
  u16* orow = out + (size_t)blockIdx.x * 3840;
  if (t >= MROWS) {
    #pragma unroll
    for (int j = 0; j < 15; ++j) orow[tid + j * 256] = 0;  // bf16 zero
    return;
  }
  int bimg = t / NTOK, n = t % NTOK;
  int gy = n / GRID_H, gx = n % GRID_H;
  float vals[15];
  float s1 = 0.f, s2 = 0.f;
  #pragma unroll
  for (int j = 0; j < 15; ++j) {
    int cout = tid + j * 256;
    int s = cout / 768, rem = cout % 768;
    int c = rem / 256, rem2 = rem % 256;
    int py = rem2 / 16, px = rem2 % 16;
    int dy = (s == 1 ? 8 : 0) - (s == 2 ? 8 : 0);
    int dx = (s == 3 ? 8 : 0) - (s == 4 ? 8 : 0);
    int Y = gy * 16 + py - dy;
    int X = gx * 16 + px - dx;
    float v = 0.f;
    if (Y >= 0 && Y < 464 && X >= 0 && X < 464)
      v = x[(((size_t)bimg * 3 + c) * 464 + Y) * 464 + X];
    vals[j] = v;
    s1 += v; s2 += v * v;
  }
  #pragma unroll
  for (int m = 1; m < 64; m <<= 1) { s1 += __shfl_xor(s1, m); s2 += __shfl_xor(s2, m); }
  __shared__ float ws1[4], ws2[4];
  int wid = tid >> 6;
  if ((tid & 63) == 0) { ws1[wid] = s1; ws2[wid] = s2; }
  __syncthreads();
  s1 = ws1[0] + ws1[1] + ws1[2] + ws1[3];
  s2 = ws2[0] + ws2[1] + ws2[2] + ws2[3];
  float mean = s1 * (1.f / 3840.f);
  float var = s2 * (1.f / 3840.f) - mean * mean;
  float rs = rsqrtf(var + 1e-5f);
  #pragma unroll
  for (int j = 0; j < 15; ++j) {
    int cout = tid + j * 256;
    orow[cout] = f2bf((vals[j] - mean) * rs * g[cout] + bsh[cout]);
  }
}

// ---------------- LayerNorm(384) fp32 -> bf16 --------------------------------
__global__ __launch_bounds__(256) void ln384(const float* __restrict__ h,
    const float* __restrict__ g, const float* __restrict__ bsh, u16* __restrict__ y) {
  int row = blockIdx.x * 4 + (threadIdx.x >> 6);
  int lane = threadIdx.x & 63;
  const float* hr = h + (size_t)row * E_;
  float v[6];
  float s1 = 0.f;
  #pragma unroll
  for (int j = 0; j < 6; ++j) { v[j] = hr[lane + j * 64]; s1 += v[j]; }
  #pragma unroll
  for (int m = 1; m < 64; m <<= 1) s1 += __shfl_xor(s1, m);
  float mean = s1 * (1.f / 384.f);
  float s2 = 0.f;
  #pragma unroll
  for (int j = 0; j < 6; ++j) { float d = v[j] - mean; s2 += d * d; }
  #pragma unroll
  for (int m = 1; m < 64; m <<= 1) s2 += __shfl_xor(s2, m);
  float rs = rsqrtf(s2 * (1.f / 384.f) + 1e-5f);
  u16* yr = y + (size_t)row * E_;
  #pragma unroll
  for (int j = 0; j < 6; ++j) {
    int c = lane + j * 64;
    yr[c] = f2bf((v[j] - mean) * rs * g[c] + bsh[c]);
  }
}

// ---------------- bf16 MFMA GEMM: C[M][N] = A[M][K] * BT[N][K]^T -------------
// EPI: 0 = bf16 out plain; 1 = bf16 out gelu(acc+bias); 2 = f32 out acc+bias;
//      3 = resid[m][n] += lscale[n]*(acc+bias[n])
template<int EPI>
__global__ __launch_bounds__(256) void gemm_bt(
    const u16* __restrict__ A, const u16* __restrict__ BT,
    int N, int K,
    const float* __restrict__ bias, const float* __restrict__ lscale,
    float* __restrict__ resid, u16* __restrict__ outb, float* __restrict__ outf) {
  __shared__ alignas(16) short As[128 * 64];
  __shared__ alignas(16) short Bs[128 * 64];
  const int m0 = blockIdx.y * 128, n0 = blockIdx.x * 128;
  const int tid = threadIdx.x;
  const int lane = tid & 63, wid = tid >> 6;
  const int wm = wid >> 1, wn = wid & 1;
  f32x4 acc[4][4] = {};
  const int nkt = K >> 6;
  for (int kt = 0; kt < nkt; ++kt) {
    __syncthreads();
    const int k0 = kt * 64;
    #pragma unroll
    for (int i = 0; i < 4; ++i) {
      int chunk = i * 4 + wid;                 // 0..15, each = 512 elems (8 rows)
      int e = (chunk << 9) + (lane << 3);
      int row = e >> 6, col = e & 63;
      const u16* ga = A + (size_t)(m0 + row) * K + k0 + col;
      const u16* gb = BT + (size_t)(n0 + row) * K + k0 + col;
      __builtin_amdgcn_global_load_lds((const __attribute__((address_space(1))) void*)ga,
          (__attribute__((address_space(3))) void*)(As + (chunk << 9)), 16, 0, 0);
      __builtin_amdgcn_global_load_lds((const __attribute__((address_space(1))) void*)gb,
          (__attribute__((address_space(3))) void*)(Bs + (chunk << 9)), 16, 0, 0);
    }
    __syncthreads();
    #pragma unroll
    for (int kk = 0; kk < 2; ++kk) {
      short8 a[4], bfr[4];
      #pragma unroll
      for (int mi = 0; mi < 4; ++mi)
        a[mi] = *(const short8*)(As + (wm * 64 + mi * 16 + (lane & 15)) * 64 + kk * 32 + ((lane >> 4) << 3));
      #pragma unroll
      for (int nj = 0; nj < 4; ++nj)
        bfr[nj] = *(const short8*)(Bs + (wn * 64 + nj * 16 + (lane & 15)) * 64 + kk * 32 + ((lane >> 4) << 3));
      #pragma unroll
      for (int mi = 0; mi < 4; ++mi)
        #pragma unroll
        for (int nj = 0; nj < 4; ++nj)
          acc[mi][nj] = __builtin_amdgcn_mfma_f32_16x16x32_bf16(a[mi], bfr[nj], acc[mi][nj], 0, 0, 0);
    }
  }
  const int rrow = (lane >> 4) << 2;
  const int ccol = lane & 15;
  #pragma unroll
  for (int mi = 0; mi < 4; ++mi)
    #pragma unroll
    for (int nj = 0; nj < 4; ++nj) {
      int gn = n0 + wn * 64 + nj * 16 + ccol;
      #pragma unroll
      for (int r = 0; r < 4; ++r) {
        int gm = m0 + wm * 64 + mi * 16 + rrow + r;
        float v = acc[mi][nj][r];
        if (EPI == 0) {
          outb[(size_t)gm * N + gn] = f2bf(v);
        } else if (EPI == 1) {
          outb[(size_t)gm * N + gn] = f2bf(gelu_exact(v + bias[gn]));
        } else if (EPI == 2) {
          outf[(size_t)gm * N + gn] = v + bias[gn];
        } else {
          float* p = resid + (size_t)gm * N + gn;
          *p = *p + lscale[gn] * (v + bias[gn]);
        }
      }
    }
}

// ---------------- flash attention, 96 (b,h) x 14 q-tiles ---------------------
__global__ __launch_bounds__(256) void attn(const u16* __restrict__ qkv,
    const float* __restrict__ temp_d, const float* __restrict__ locw_d,
    u16* __restrict__ o) {
  const int qt = blockIdx.x;           // 0..13
  const int bh = blockIdx.y;           // 0..95
  const int bimg = bh / NH_, hh = bh % NH_;
  const int tid = threadIdx.x, lane = tid & 63, w = tid >> 6;
  const float scale = __expf(temp_d[hh]);
  const float lw = locw_d[hh];

  __shared__ alignas(16) short vt[64][72];        // V^T tile [hd][tok]
  __shared__ alignas(16) short pl[4][16][72];     // per-wave P [qrow][tok]

  // Q fragments (A-frag: row = lane&15, k = (lane>>4)*8 + i)
  int qrow_local = qt * 64 + w * 16 + (lane & 15);
  int qrow_c = qrow_local < NTOK ? qrow_local : NTOK - 1;
  const u16* qptr = qkv + ((size_t)(bimg * NTOK + qrow_c)) * 1152 + hh * 64;
  short8 qf0 = *(const short8*)(qptr + ((lane >> 4) << 3));
  short8 qf1 = *(const short8*)(qptr + 32 + ((lane >> 4) << 3));

  float qy[4], qx[4];
  #pragma unroll
  for (int r = 0; r < 4; ++r) {
    int iq = qt * 64 + w * 16 + ((lane >> 4) << 2) + r;
    if (iq >= NTOK) iq = NTOK - 1;
    qy[r] = (float)(iq / GRID_H) * (1.f / 28.f);
    qx[r] = (float)(iq % GRID_H) * (1.f / 28.f);
  }

  f32x4 of[4] = {};
  float mrow[4], lrow[4];
  #pragma unroll
  for (int r = 0; r < 4; ++r) { mrow[r] = -1e30f; lrow[r] = 0.f; }

  for (int kt = 0; kt < 14; ++kt) {
    __syncthreads();
    // stage V^T: thread -> (tok = tid>>2, hd0 = (tid&3)*16)
    {
      int tok = tid >> 2, hd0 = (tid & 3) << 4;
      int krow = bimg * NTOK + kt * 64 + tok;
      if (krow >= MP) krow = MP - 1;
      const u16* vrow = qkv + (size_t)krow * 1152 + 768 + hh * 64 + hd0;
      short8 v0 = *(const short8*)(vrow);
      short8 v1 = *(const short8*)(vrow + 8);
      #pragma unroll
      for (int jj = 0; jj < 8; ++jj) vt[hd0 + jj][tok] = v0[jj];
      #pragma unroll
      for (int jj = 0; jj < 8; ++jj) vt[hd0 + 8 + jj][tok] = v1[jj];
    }
    __syncthreads();

    // S = Q K^T (per wave: 16 q-rows x 64 k-tokens)
    f32x4 sf[4];
    #pragma unroll
    for (int nt = 0; nt < 4; ++nt) {
      f32x4 z = {0.f, 0.f, 0.f, 0.f};
      sf[nt] = z;
      int ktok = kt * 64 + nt * 16 + (lane & 15);
      int krow = bimg * NTOK + ktok;
      if (krow >= MP) krow = MP - 1;
      const u16* kptr = qkv + (size_t)krow * 1152 + 384 + hh * 64;
      short8 kf0 = *(const short8*)(kptr + ((lane >> 4) << 3));
      short8 kf1 = *(const short8*)(kptr + 32 + ((lane >> 4) << 3));
      sf[nt] = __builtin_amdgcn_mfma_f32_16x16x32_bf16(qf0, kf0, sf[nt], 0, 0, 0);
      sf[nt] = __builtin_amdgcn_mfma_f32_16x16x32_bf16(qf1, kf1, sf[nt], 0, 0, 0);
    }

    // scale + locality bias + tail mask
    float pv[4][4];
    #pragma unroll
    for (int nt = 0; nt < 4; ++nt) {
      int j = kt * 64 + nt * 16 + (lane & 15);
      bool valid = j < NTOK;
      int jc = valid ? j : NTOK - 1;
      float jy = (float)(jc / GRID_H) * (1.f / 28.f);
      float jx = (float)(jc % GRID_H) * (1.f / 28.f);
      #pragma unroll
      for (int r = 0; r < 4; ++r) {
        float dy = qy[r] - jy, dx = qx[r] - jx;
        float val = sf[nt][r] * scale + lw * (-0.5f * (dy * dy + dx * dx));
        pv[nt][r] = valid ? val : -1e30f;
      }
    }

    // online softmax per q-row (row lives across the 16 lanes of a lane>>4 group)
    #pragma unroll
    for (int r = 0; r < 4; ++r) {
      float tmax = fmaxf(fmaxf(pv[0][r], pv[1][r]), fmaxf(pv[2][r], pv[3][r]));
      #pragma unroll
      for (int m = 1; m < 16; m <<= 1) tmax = fmaxf(tmax, __shfl_xor(tmax, m));
      float mnew = fmaxf(mrow[r], tmax);
      float rsum = 0.f;
      #pragma unroll
      for (int nt = 0; nt < 4; ++nt) {
        float p = __expf(pv[nt][r] - mnew);
        pv[nt][r] = p; rsum += p;
      }
      #pragma unroll
      for (int m = 1; m < 16; m <<= 1) rsum += __shfl_xor(rsum, m);
      float alpha = __expf(mrow[r] - mnew);
      lrow[r] = lrow[r] * alpha + rsum;
      mrow[r] = mnew;
      #pragma unroll
      for (int nt2 = 0; nt2 < 4; ++nt2) of[nt2][r] *= alpha;
    }

    // P -> LDS (C-layout) then read back as A-fragments
    #pragma unroll
    for (int nt = 0; nt < 4; ++nt)
      #pragma unroll
      for (int r = 0; r < 4; ++r)
        pl[w][((lane >> 4) << 2) + r][nt * 16 + (lane & 15)] = (short)f2bf(pv[nt][r]);
    asm volatile("s_waitcnt lgkmcnt(0)" ::: "memory");
    __builtin_amdgcn_sched_barrier(0);
    short8 pa0 = *(const short8*)(&pl[w][lane & 15][(lane >> 4) << 3]);
    short8 pa1 = *(const short8*)(&pl[w][lane & 15][32 + ((lane >> 4) << 3)]);

    // O += P V
    #pragma unroll
    for (int nt2 = 0; nt2 < 4; ++nt2) {
      short8 vf0 = *(const short8*)(&vt[nt2 * 16 + (lane & 15)][(lane >> 4) << 3]);
      short8 vf1 = *(const short8*)(&vt[nt2 * 16 + (lane & 15)][32 + ((lane >> 4) << 3)]);
      of[nt2] = __builtin_amdgcn_mfma_f32_16x16x32_bf16(pa0, vf0, of[nt2], 0, 0, 0);
      of[nt2] = __builtin_amdgcn_mfma_f32_16x16x32_bf16(pa1, vf1, of[nt2], 0, 0, 0);
    }
  }

  #pragma unroll
  for (int r = 0; r < 4; ++r) {
    int iq = qt * 64 + w * 16 + ((lane >> 4) << 2) + r;
    if (iq < NTOK) {
      float rl = 1.f / lrow[r];
      #pragma unroll
      for (int nt2 = 0; nt2 < 4; ++nt2)
        o[((size_t)(bimg * NTOK + iq)) * E_ + hh * 64 + nt2 * 16 + (lane & 15)] =
            f2bf(of[nt2][r] * rl);
    }
  }
}

// ---------------- final copy h[0:13456] -> out -------------------------------
__global__ __launch_bounds__(256) void copy_out(const float* __restrict__ h, float* __restrict__ out) {
  size_t i = (size_t)blockIdx.x * 256 + threadIdx.x;
  if (i < (size_t)MROWS * E_) out[i] = h[i];
}

extern "C" void kernel_launch(void* const* d_in, const int* in_sizes, int n_in,
                              void* d_out, int out_size, void* d_ws, size_t ws_size,
                              hipStream_t stream) {
  const float* x      = (const float*)d_in[0];
  const float* tok_ng = (const float*)d_in[1];
  const float* tok_nb = (const float*)d_in[2];
  const float* tok_w1 = (const float*)d_in[3];
  const float* tok_b1 = (const float*)d_in[4];
  const float* tok_w2 = (const float*)d_in[5];
  const float* tok_b2 = (const float*)d_in[6];
  const float* ln1_g  = (const float*)d_in[7];
  const float* ln1_b  = (const float*)d_in[8];
  const float* w_qkv  = (const float*)d_in[9];
  const float* temp   = (const float*)d_in[10];
  const float* loc_w  = (const float*)d_in[11];
  const float* w_proj = (const float*)d_in[12];
  const float* b_proj = (const float*)d_in[13];
  const float* ls1    = (const float*)d_in[14];
  const float* ln2_g  = (const float*)d_in[15];
  const float* ln2_b  = (const float*)d_in[16];
  const float* ff_w1  = (const float*)d_in[17];
  const float* ff_b1  = (const float*)d_in[18];
  const float* ff_w2  = (const float*)d_in[19];
  const float* ff_b2  = (const float*)d_in[20];
  const float* ls2    = (const float*)d_in[21];
  float* out = (float*)d_out;

  char* ws = (char*)d_ws;
  size_t off = 0;
  auto alloc = [&](size_t bytes) -> void* {
    void* p = ws + off; off += (bytes + 255) & ~(size_t)255; return p;
  };
  // weights (persistent per launch)
  u16* w1T   = (u16*)alloc(768UL * 3840 * 2);
  u16* w2T   = (u16*)alloc(384UL * 768 * 2);
  u16* qkvT  = (u16*)alloc(8UL * 1152 * 384 * 2);
  u16* projT = (u16*)alloc(8UL * 384 * 384 * 2);
  u16* f1T   = (u16*)alloc(8UL * 1536 * 384 * 2);
  u16* f2T   = (u16*)alloc(8UL * 384 * 1536 * 2);
  // persistent activation
  float* h   = (float*)alloc((size_t)MP * 384 * 4);
  // regB: h1 (embed phase) OR y+ob (block phase)  -- MP*768*2 bytes
  char* regB = (char*)alloc((size_t)MP * 768 * 2);
  u16* h1 = (u16*)regB;
  u16* y  = (u16*)regB;
  u16* ob = (u16*)(regB + (size_t)MP * 384 * 2);
  // regA: Xlnc (embed) OR qkvb (attn) OR f1b (ff)  -- MP*1536*2 bytes
  char* regA = (char*)alloc((size_t)MP * 1536 * 2);
  u16* Xlnc = (u16*)regA;   // CM*3840*2 = 15.7MB <= 41.7MB
  u16* qkvb = (u16*)regA;   // MP*1152*2 = 31.3MB <= 41.7MB
  u16* f1b  = (u16*)regA;   // MP*1536*2 = 41.7MB
  (void)in_sizes; (void)n_in; (void)out_size;

  if (off > ws_size) return;  // diagnostic: leaves d_out untouched -> absmax ~2.5

  // weight transposes (fp32 [K][N] -> bf16 [N][K])
  transpose_conv<<<dim3(24, 120, 1), 256, 0, stream>>>(tok_w1, w1T, 3840, 768);
  transpose_conv<<<dim3(12, 24, 1), 256, 0, stream>>>(tok_w2, w2T, 768, 384);
  transpose_conv<<<dim3(36, 12, 8), 256, 0, stream>>>(w_qkv, qkvT, 384, 1152);
  transpose_conv<<<dim3(12, 12, 8), 256, 0, stream>>>(w_proj, projT, 384, 384);
  transpose_conv<<<dim3(48, 12, 8), 256, 0, stream>>>(ff_w1, f1T, 384, 1536);
  transpose_conv<<<dim3(12, 48, 8), 256, 0, stream>>>(ff_w2, f2T, 1536, 384);

  // patch embed + LN(3840) + first GEMM, chunked through Xlnc
  for (int m = 0; m < MP; m += CM) {
    int rows = MP - m; if (rows > CM) rows = CM;
    patch_ln<<<rows, 256, 0, stream>>>(x, tok_ng, tok_nb, Xlnc, m);
    gemm_bt<1><<<dim3(6, rows / 128), 256, 0, stream>>>(Xlnc, w1T, 768, 3840,
        tok_b1, nullptr, nullptr, h1 + (size_t)m * 768, nullptr);
  }
  gemm_bt<2><<<dim3(3, MP / 128), 256, 0, stream>>>(h1, w2T, 384, 768, tok_b2, nullptr, nullptr, nullptr, h);

  for (int d = 0; d < 8; ++d) {
    ln384<<<MP / 4, 256, 0, stream>>>(h, ln1_g + d * E_, ln1_b + d * E_, y);
    gemm_bt<0><<<dim3(9, MP / 128), 256, 0, stream>>>(y, qkvT + (size_t)d * 1152 * 384, 1152, 384, nullptr, nullptr, nullptr, qkvb, nullptr);
    attn<<<dim3(14, 96), 256, 0, stream>>>(qkvb, temp + d * NH_, loc_w + d * NH_, ob);
    gemm_bt<3><<<dim3(3, MP / 128), 256, 0, stream>>>(ob, projT + (size_t)d * 384 * 384, 384, 384, b_proj + d * E_, ls1 + d * E_, h, nullptr, nullptr);
    ln384<<<MP / 4, 256, 0, stream>>>(h, ln2_g + d * E_, ln2_b + d * E_, y);
    gemm_bt<1><<<dim3(12, MP / 128), 256, 0, stream>>>(y, f1T + (size_t)d * 1536 * 384, 1536, 384, ff_b1 + d * 1536, nullptr, nullptr, f1b, nullptr);
    gemm_bt<3><<<dim3(3, MP / 128), 256, 0, stream>>>(f1b, f2T + (size_t)d * 384 * 1536, 384, 1536, ff_b2 + d * E_, ls2 + d * E_, h, nullptr, nullptr);
  }

  copy_out<<<(MROWS * E_ + 255) / 256, 256, 0, stream>>>(h, out);
}

// Round 3
// 2614.072 us; speedup vs baseline: 1.1810x; 1.1810x over previous
//
#include <hip/hip_runtime.h>
#include <math.h>

typedef __attribute__((ext_vector_type(8))) short short8;
typedef __attribute__((ext_vector_type(4))) float f32x4;
typedef unsigned short u16;

#define NTOK 841
#define GRID_H 29
#define E_ 384
#define NH_ 6
#define MROWS 13456
#define MP 13568
#define CM 5120
#define KB 128
#define KT7 7

__device__ __forceinline__ u16 f2bf(float f) {
  union { float f; unsigned int u; } c; c.f = f;
  unsigned int u = c.u;
  return (u16)((u + 0x7fffu + ((u >> 16) & 1u)) >> 16);
}

__device__ __forceinline__ float gelu_exact(float v) {
  return 0.5f * v * (1.f + erff(v * 0.70710678118654752440f));
}

// byte offset in a [rows][128]-bf16 LDS tile (256B/row), 16B-chunk XOR swizzle
__device__ __forceinline__ int swz(int row, int col) {
  return row * 256 + ((((col >> 3) ^ (row & 7)) << 4) | ((col & 7) << 1));
}

// ---------------- transpose + fp32->bf16 convert: in [K][N] -> out [N][K] ----
__global__ __launch_bounds__(256) void transpose_conv(const float* __restrict__ in,
    u16* __restrict__ out, int K, int N) {
  __shared__ float tile[32][33];
  size_t zo = (size_t)blockIdx.z * K * N;
  const float* inp = in + zo;
  u16* outp = out + zo;
  int n0 = blockIdx.x * 32, k0 = blockIdx.y * 32;
  int tx = threadIdx.x & 31, ty = threadIdx.x >> 5;
  #pragma unroll
  for (int r = ty; r < 32; r += 8) tile[r][tx] = inp[(size_t)(k0 + r) * N + n0 + tx];
  __syncthreads();
  #pragma unroll
  for (int r = ty; r < 32; r += 8) outp[(size_t)(n0 + r) * K + k0 + tx] = f2bf(tile[tx][r]);
}

// ---------------- fused 5-shift patchify + LayerNorm(3840) -> bf16 ----------
__global__ __launch_bounds__(256) void patch_ln(const float* __restrict__ x,
    const float* __restrict__ g, const float* __restrict__ bsh, u16* __restrict__ out,
    int t0) {
  int t = t0 + blockIdx.x;
  int tid = threadIdx.x;
  u16* orow = out + (size_t)blockIdx.x * 3840;
  if (t >= MROWS) {
    #pragma unroll
    for (int j = 0; j < 15; ++j) orow[tid + j * 256] = 0;  // bf16 zero
    return;
  }
  int bimg = t / NTOK, n = t % NTOK;
  int gy = n / GRID_H, gx = n % GRID_H;
  float vals[15];
  float s1 = 0.f, s2 = 0.f;
  #pragma unroll
  for (int j = 0; j < 15; ++j) {
    int cout = tid + j * 256;
    int s = cout / 768, rem = cout % 768;
    int c = rem / 256, rem2 = rem % 256;
    int py = rem2 / 16, px = rem2 % 16;
    int dy = (s == 1 ? 8 : 0) - (s == 2 ? 8 : 0);
    int dx = (s == 3 ? 8 : 0) - (s == 4 ? 8 : 0);
    int Y = gy * 16 + py - dy;
    int X = gx * 16 + px - dx;
    float v = 0.f;
    if (Y >= 0 && Y < 464 && X >= 0 && X < 464)
      v = x[(((size_t)bimg * 3 + c) * 464 + Y) * 464 + X];
    vals[j] = v;
    s1 += v; s2 += v * v;
  }
  #pragma unroll
  for (int m = 1; m < 64; m <<= 1) { s1 += __shfl_xor(s1, m); s2 += __shfl_xor(s2, m); }
  __shared__ float ws1[4], ws2[4];
  int wid = tid >> 6;
  if ((tid & 63) == 0) { ws1[wid] = s1; ws2[wid] = s2; }
  __syncthreads();
  s1 = ws1[0] + ws1[1] + ws1[2] + ws1[3];
  s2 = ws2[0] + ws2[1] + ws2[2] + ws2[3];
  float mean = s1 * (1.f / 3840.f);
  float var = s2 * (1.f / 3840.f) - mean * mean;
  float rs = rsqrtf(var + 1e-5f);
  #pragma unroll
  for (int j = 0; j < 15; ++j) {
    int cout = tid + j * 256;
    orow[cout] = f2bf((vals[j] - mean) * rs * g[cout] + bsh[cout]);
  }
}

// ---------------- LayerNorm(384) fp32 -> bf16 --------------------------------
__global__ __launch_bounds__(256) void ln384(const float* __restrict__ h,
    const float* __restrict__ g, const float* __restrict__ bsh, u16* __restrict__ y) {
  int row = blockIdx.x * 4 + (threadIdx.x >> 6);
  int lane = threadIdx.x & 63;
  const float* hr = h + (size_t)row * E_;
  float v[6];
  float s1 = 0.f;
  #pragma unroll
  for (int j = 0; j < 6; ++j) { v[j] = hr[lane + j * 64]; s1 += v[j]; }
  #pragma unroll
  for (int m = 1; m < 64; m <<= 1) s1 += __shfl_xor(s1, m);
  float mean = s1 * (1.f / 384.f);
  float s2 = 0.f;
  #pragma unroll
  for (int j = 0; j < 6; ++j) { float d = v[j] - mean; s2 += d * d; }
  #pragma unroll
  for (int m = 1; m < 64; m <<= 1) s2 += __shfl_xor(s2, m);
  float rs = rsqrtf(s2 * (1.f / 384.f) + 1e-5f);
  u16* yr = y + (size_t)row * E_;
  #pragma unroll
  for (int j = 0; j < 6; ++j) {
    int c = lane + j * 64;
    yr[c] = f2bf((v[j] - mean) * rs * g[c] + bsh[c]);
  }
}

// ---------------- bf16 MFMA GEMM: C[M][N] = A[M][K] * BT[N][K]^T -------------
// EPI: 0 = bf16 out plain; 1 = bf16 out gelu(acc+bias); 2 = f32 out acc+bias;
//      3 = resid[m][n] += lscale[n]*(acc+bias[n])
template<int EPI>
__global__ __launch_bounds__(256) void gemm_bt(
    const u16* __restrict__ A, const u16* __restrict__ BT,
    int N, int K,
    const float* __restrict__ bias, const float* __restrict__ lscale,
    float* __restrict__ resid, u16* __restrict__ outb, float* __restrict__ outf) {
  __shared__ alignas(16) short As[128 * 64];
  __shared__ alignas(16) short Bs[128 * 64];
  // bijective XCD swizzle (m204): cluster consecutive work on one XCD
  const int gx = gridDim.x;
  const int nwg = gx * gridDim.y;
  {
  }
  int L = blockIdx.x + blockIdx.y * gx;
  int q8 = nwg >> 3, r8 = nwg & 7, xcd = L & 7, pos = L >> 3;
  int L2 = (xcd < r8 ? xcd * (q8 + 1) : r8 * (q8 + 1) + (xcd - r8) * q8) + pos;
  const int m0 = (L2 / gx) * 128, n0 = (L2 % gx) * 128;
  const int tid = threadIdx.x;
  const int lane = tid & 63, wid = tid >> 6;
  const int wm = wid >> 1, wn = wid & 1;
  f32x4 acc[4][4] = {};
  const int nkt = K >> 6;
  for (int kt = 0; kt < nkt; ++kt) {
    __syncthreads();
    const int k0 = kt * 64;
    #pragma unroll
    for (int i = 0; i < 4; ++i) {
      int chunk = i * 4 + wid;                 // 0..15, each = 512 elems (8 rows)
      int e = (chunk << 9) + (lane << 3);
      int row = e >> 6, col = e & 63;
      const u16* ga = A + (size_t)(m0 + row) * K + k0 + col;
      const u16* gb = BT + (size_t)(n0 + row) * K + k0 + col;
      __builtin_amdgcn_global_load_lds((const __attribute__((address_space(1))) void*)ga,
          (__attribute__((address_space(3))) void*)(As + (chunk << 9)), 16, 0, 0);
      __builtin_amdgcn_global_load_lds((const __attribute__((address_space(1))) void*)gb,
          (__attribute__((address_space(3))) void*)(Bs + (chunk << 9)), 16, 0, 0);
    }
    __syncthreads();
    #pragma unroll
    for (int kk = 0; kk < 2; ++kk) {
      short8 a[4], bfr[4];
      #pragma unroll
      for (int mi = 0; mi < 4; ++mi)
        a[mi] = *(const short8*)(As + (wm * 64 + mi * 16 + (lane & 15)) * 64 + kk * 32 + ((lane >> 4) << 3));
      #pragma unroll
      for (int nj = 0; nj < 4; ++nj)
        bfr[nj] = *(const short8*)(Bs + (wn * 64 + nj * 16 + (lane & 15)) * 64 + kk * 32 + ((lane >> 4) << 3));
      #pragma unroll
      for (int mi = 0; mi < 4; ++mi)
        #pragma unroll
        for (int nj = 0; nj < 4; ++nj)
          acc[mi][nj] = __builtin_amdgcn_mfma_f32_16x16x32_bf16(a[mi], bfr[nj], acc[mi][nj], 0, 0, 0);
    }
  }
  const int rrow = (lane >> 4) << 2;
  const int ccol = lane & 15;
  #pragma unroll
  for (int mi = 0; mi < 4; ++mi)
    #pragma unroll
    for (int nj = 0; nj < 4; ++nj) {
      int gn = n0 + wn * 64 + nj * 16 + ccol;
      #pragma unroll
      for (int r = 0; r < 4; ++r) {
        int gm = m0 + wm * 64 + mi * 16 + rrow + r;
        float v = acc[mi][nj][r];
        if (EPI == 0) {
          outb[(size_t)gm * N + gn] = f2bf(v);
        } else if (EPI == 1) {
          outb[(size_t)gm * N + gn] = f2bf(gelu_exact(v + bias[gn]));
        } else if (EPI == 2) {
          outf[(size_t)gm * N + gn] = v + bias[gn];
        } else {
          float* p = resid + (size_t)gm * N + gn;
          *p = *p + lscale[gn] * (v + bias[gn]);
        }
      }
    }
}

// ---------------- flash attention, KVBLK=128, swizzled LDS, dbuf V -----------
__global__ __launch_bounds__(256) void attn(const u16* __restrict__ qkv,
    const float* __restrict__ temp_d, const float* __restrict__ locw_d,
    u16* __restrict__ o) {
  // XCD swizzle: 1344 = 8 * 168; all 14 q-tiles of one (b,h) on one XCD
  int Lw = blockIdx.x + blockIdx.y * 14;
  int L2 = (Lw & 7) * 168 + (Lw >> 3);
  const int qt = L2 % 14, bh = L2 / 14;
  const int bimg = bh / NH_, hh = bh % NH_;
  const int tid = threadIdx.x, lane = tid & 63, w = tid >> 6;
  const int lg = lane >> 4, lc = lane & 15;
  const float scale = __expf(temp_d[hh]);
  const float lw = locw_d[hh];

  __shared__ alignas(16) char vt[2][64 * 256];    // V^T [hd][tok], swizzled, dbuf
  __shared__ alignas(16) char pl[4][16 * 256];    // per-wave P [q][tok], swizzled

  // Q fragments (A-frag: row = lc, k = lg*8 + j)
  int qrow_local = qt * 64 + w * 16 + lc;
  int qrow_c = qrow_local < NTOK ? qrow_local : NTOK - 1;
  const u16* qptr = qkv + ((size_t)(bimg * NTOK + qrow_c)) * 1152 + hh * 64;
  short8 qf0 = *(const short8*)(qptr + (lg << 3));
  short8 qf1 = *(const short8*)(qptr + 32 + (lg << 3));

  float qy[4], qx[4];
  #pragma unroll
  for (int r = 0; r < 4; ++r) {
    int iq = qt * 64 + w * 16 + (lg << 2) + r;
    if (iq >= NTOK) iq = NTOK - 1;
    qy[r] = (float)(iq / GRID_H) * (1.f / 28.f);
    qx[r] = (float)(iq % GRID_H) * (1.f / 28.f);
  }

  f32x4 of[4] = {};
  float mrow[4], lrow[4];
  #pragma unroll
  for (int r = 0; r < 4; ++r) { mrow[r] = -1e30f; lrow[r] = 0.f; }

  // V staging: thread owns token-pair vp (2 toks) x 16 hd rows [hdb, hdb+16)
  const int vp = tid & 63, hdb = (tid >> 6) << 4;
  short8 vr0, vr1, vr2, vr3;
  auto vload = [&](int kt) {
    int t0 = kt * KB + 2 * vp;
    int r0 = t0 < NTOK ? t0 : NTOK - 1;
    int r1 = t0 + 1 < NTOK ? t0 + 1 : NTOK - 1;
    const u16* p0 = qkv + (size_t)(bimg * NTOK + r0) * 1152 + 768 + hh * 64 + hdb;
    const u16* p1 = qkv + (size_t)(bimg * NTOK + r1) * 1152 + 768 + hh * 64 + hdb;
    vr0 = *(const short8*)p0; vr1 = *(const short8*)(p0 + 8);
    vr2 = *(const short8*)p1; vr3 = *(const short8*)(p1 + 8);
  };
  auto vwrite = [&](int b) {
    char* base = vt[b];
    #pragma unroll
    for (int j = 0; j < 8; ++j) {
      unsigned int u = (unsigned int)(unsigned short)vr0[j] |
                       ((unsigned int)(unsigned short)vr2[j] << 16);
      *(unsigned int*)(base + swz(hdb + j, 2 * vp)) = u;
    }
    #pragma unroll
    for (int j = 0; j < 8; ++j) {
      unsigned int u = (unsigned int)(unsigned short)vr1[j] |
                       ((unsigned int)(unsigned short)vr3[j] << 16);
      *(unsigned int*)(base + swz(hdb + 8 + j, 2 * vp)) = u;
    }
  };

  vload(0);
  vwrite(0);
  __syncthreads();

  for (int kt = 0; kt < KT7; ++kt) {
    const int cur = kt & 1;

    // S = Q K^T : 8 nt of 16 tokens
    f32x4 sf[8];
    #pragma unroll
    for (int nt = 0; nt < 8; ++nt) {
      int ktok = kt * KB + nt * 16 + lc;
      int kr = ktok < NTOK ? ktok : NTOK - 1;
      const u16* kp = qkv + (size_t)(bimg * NTOK + kr) * 1152 + 384 + hh * 64;
      short8 kf0 = *(const short8*)(kp + (lg << 3));
      short8 kf1 = *(const short8*)(kp + 32 + (lg << 3));
      f32x4 z = {0.f, 0.f, 0.f, 0.f};
      z = __builtin_amdgcn_mfma_f32_16x16x32_bf16(qf0, kf0, z, 0, 0, 0);
      z = __builtin_amdgcn_mfma_f32_16x16x32_bf16(qf1, kf1, z, 0, 0, 0);
      sf[nt] = z;
    }

    if (kt + 1 < KT7) vload(kt + 1);   // issue next V loads early (T14)

    // scale + locality bias + tail mask
    float pv[8][4];
    #pragma unroll
    for (int nt = 0; nt < 8; ++nt) {
      int j = kt * KB + nt * 16 + lc;
      bool valid = j < NTOK;
      unsigned jc = valid ? (unsigned)j : (NTOK - 1);
      float jy = (float)(jc / 29u) * (1.f / 28.f);
      float jx = (float)(jc % 29u) * (1.f / 28.f);
      #pragma unroll
      for (int r = 0; r < 4; ++r) {
        float dy = qy[r] - jy, dx = qx[r] - jx;
        float val = sf[nt][r] * scale - lw * 0.5f * (dy * dy + dx * dx);
        pv[nt][r] = valid ? val : -1e30f;
      }
    }

    // online softmax per q-row (row across 16 lanes of a lg-group)
    #pragma unroll
    for (int r = 0; r < 4; ++r) {
      float t0 = fmaxf(pv[0][r], pv[1][r]);
      float t1 = fmaxf(pv[2][r], pv[3][r]);
      float t2 = fmaxf(pv[4][r], pv[5][r]);
      float t3 = fmaxf(pv[6][r], pv[7][r]);
      float tmax = fmaxf(fmaxf(t0, t1), fmaxf(t2, t3));
      #pragma unroll
      for (int m = 1; m < 16; m <<= 1) tmax = fmaxf(tmax, __shfl_xor(tmax, m));
      float mnew = fmaxf(mrow[r], tmax);
      float rsum = 0.f;
      #pragma unroll
      for (int nt = 0; nt < 8; ++nt) {
        float p = __expf(pv[nt][r] - mnew);
        pv[nt][r] = p; rsum += p;
      }
      #pragma unroll
      for (int m = 1; m < 16; m <<= 1) rsum += __shfl_xor(rsum, m);
      float alpha = __expf(mrow[r] - mnew);
      lrow[r] = lrow[r] * alpha + rsum;
      mrow[r] = mnew;
      of[0][r] *= alpha; of[1][r] *= alpha; of[2][r] *= alpha; of[3][r] *= alpha;
    }

    // P -> LDS (swizzled) then read back as A-fragments
    char* plw = pl[w];
    #pragma unroll
    for (int nt = 0; nt < 8; ++nt)
      #pragma unroll
      for (int r = 0; r < 4; ++r)
        *(u16*)(plw + swz((lg << 2) + r, nt * 16 + lc)) = f2bf(pv[nt][r]);
    asm volatile("s_waitcnt lgkmcnt(0)" ::: "memory");
    __builtin_amdgcn_sched_barrier(0);
    short8 pa[4];
    #pragma unroll
    for (int t = 0; t < 4; ++t)
      pa[t] = *(const short8*)(plw + swz(lc, t * 32 + (lg << 3)));

    // O += P V
    const char* vb = vt[cur];
    #pragma unroll
    for (int n2 = 0; n2 < 4; ++n2) {
      f32x4 accv = of[n2];
      #pragma unroll
      for (int t = 0; t < 4; ++t) {
        short8 vf = *(const short8*)(vb + swz(n2 * 16 + lc, t * 32 + (lg << 3)));
        accv = __builtin_amdgcn_mfma_f32_16x16x32_bf16(pa[t], vf, accv, 0, 0, 0);
      }
      of[n2] = accv;
    }

    if (kt + 1 < KT7) vwrite(cur ^ 1);  // LDS-write next V after PV
    __syncthreads();
  }

  #pragma unroll
  for (int r = 0; r < 4; ++r) {
    int iq = qt * 64 + w * 16 + (lg << 2) + r;
    if (iq < NTOK) {
      float rl = 1.f / lrow[r];
      #pragma unroll
      for (int n2 = 0; n2 < 4; ++n2)
        o[((size_t)(bimg * NTOK + iq)) * E_ + hh * 64 + n2 * 16 + lc] =
            f2bf(of[n2][r] * rl);
    }
  }
}

// ---------------- final copy h[0:13456] -> out -------------------------------
__global__ __launch_bounds__(256) void copy_out(const float* __restrict__ h, float* __restrict__ out) {
  size_t i = (size_t)blockIdx.x * 256 + threadIdx.x;
  if (i < (size_t)MROWS * E_) out[i] = h[i];
}

extern "C" void kernel_launch(void* const* d_in, const int* in_sizes, int n_in,
                              void* d_out, int out_size, void* d_ws, size_t ws_size,
                              hipStream_t stream) {
  const float* x      = (const float*)d_in[0];
  const float* tok_ng = (const float*)d_in[1];
  const float* tok_nb = (const float*)d_in[2];
  const float* tok_w1 = (const float*)d_in[3];
  const float* tok_b1 = (const float*)d_in[4];
  const float* tok_w2 = (const float*)d_in[5];
  const float* tok_b2 = (const float*)d_in[6];
  const float* ln1_g  = (const float*)d_in[7];
  const float* ln1_b  = (const float*)d_in[8];
  const float* w_qkv  = (const float*)d_in[9];
  const float* temp   = (const float*)d_in[10];
  const float* loc_w  = (const float*)d_in[11];
  const float* w_proj = (const float*)d_in[12];
  const float* b_proj = (const float*)d_in[13];
  const float* ls1    = (const float*)d_in[14];
  const float* ln2_g  = (const float*)d_in[15];
  const float* ln2_b  = (const float*)d_in[16];
  const float* ff_w1  = (const float*)d_in[17];
  const float* ff_b1  = (const float*)d_in[18];
  const float* ff_w2  = (const float*)d_in[19];
  const float* ff_b2  = (const float*)d_in[20];
  const float* ls2    = (const float*)d_in[21];
  float* out = (float*)d_out;

  char* ws = (char*)d_ws;
  size_t off = 0;
  auto alloc = [&](size_t bytes) -> void* {
    void* p = ws + off; off += (bytes + 255) & ~(size_t)255; return p;
  };
  // weights (persistent per launch)
  u16* w1T   = (u16*)alloc(768UL * 3840 * 2);
  u16* w2T   = (u16*)alloc(384UL * 768 * 2);
  u16* qkvT  = (u16*)alloc(8UL * 1152 * 384 * 2);
  u16* projT = (u16*)alloc(8UL * 384 * 384 * 2);
  u16* f1T   = (u16*)alloc(8UL * 1536 * 384 * 2);
  u16* f2T   = (u16*)alloc(8UL * 384 * 1536 * 2);
  // persistent activation
  float* h   = (float*)alloc((size_t)MP * 384 * 4);
  // regB: h1 (embed phase) OR y+ob (block phase)
  char* regB = (char*)alloc((size_t)MP * 768 * 2);
  u16* h1 = (u16*)regB;
  u16* y  = (u16*)regB;
  u16* ob = (u16*)(regB + (size_t)MP * 384 * 2);
  // regA: Xlnc (embed) OR qkvb (attn) OR f1b (ff)
  char* regA = (char*)alloc((size_t)MP * 1536 * 2);
  u16* Xlnc = (u16*)regA;   // CM*3840*2 = 39.3MB <= 41.7MB
  u16* qkvb = (u16*)regA;
  u16* f1b  = (u16*)regA;
  (void)in_sizes; (void)n_in; (void)out_size;

  if (off > ws_size) return;  // diagnostic: leaves d_out untouched -> absmax ~2.5

  // weight transposes (fp32 [K][N] -> bf16 [N][K])
  transpose_conv<<<dim3(24, 120, 1), 256, 0, stream>>>(tok_w1, w1T, 3840, 768);
  transpose_conv<<<dim3(12, 24, 1), 256, 0, stream>>>(tok_w2, w2T, 768, 384);
  transpose_conv<<<dim3(36, 12, 8), 256, 0, stream>>>(w_qkv, qkvT, 384, 1152);
  transpose_conv<<<dim3(12, 12, 8), 256, 0, stream>>>(w_proj, projT, 384, 384);
  transpose_conv<<<dim3(48, 12, 8), 256, 0, stream>>>(ff_w1, f1T, 384, 1536);
  transpose_conv<<<dim3(12, 48, 8), 256, 0, stream>>>(ff_w2, f2T, 1536, 384);

  // patch embed + LN(3840) + first GEMM, chunked through Xlnc
  for (int m = 0; m < MP; m += CM) {
    int rows = MP - m; if (rows > CM) rows = CM;
    patch_ln<<<rows, 256, 0, stream>>>(x, tok_ng, tok_nb, Xlnc, m);
    gemm_bt<1><<<dim3(6, rows / 128), 256, 0, stream>>>(Xlnc, w1T, 768, 3840,
        tok_b1, nullptr, nullptr, h1 + (size_t)m * 768, nullptr);
  }
  gemm_bt<2><<<dim3(3, MP / 128), 256, 0, stream>>>(h1, w2T, 384, 768, tok_b2, nullptr, nullptr, nullptr, h);

  for (int d = 0; d < 8; ++d) {
    ln384<<<MP / 4, 256, 0, stream>>>(h, ln1_g + d * E_, ln1_b + d * E_, y);
    gemm_bt<0><<<dim3(9, MP / 128), 256, 0, stream>>>(y, qkvT + (size_t)d * 1152 * 384, 1152, 384, nullptr, nullptr, nullptr, qkvb, nullptr);
    attn<<<dim3(14, 96), 256, 0, stream>>>(qkvb, temp + d * NH_, loc_w + d * NH_, ob);
    gemm_bt<3><<<dim3(3, MP / 128), 256, 0, stream>>>(ob, projT + (size_t)d * 384 * 384, 384, 384, b_proj + d * E_, ls1 + d * E_, h, nullptr, nullptr);
    ln384<<<MP / 4, 256, 0, stream>>>(h, ln2_g + d * E_, ln2_b + d * E_, y);
    gemm_bt<1><<<dim3(12, MP / 128), 256, 0, stream>>>(y, f1T + (size_t)d * 1536 * 384, 1536, 384, ff_b1 + d * 1536, nullptr, nullptr, f1b, nullptr);
    gemm_bt<3><<<dim3(3, MP / 128), 256, 0, stream>>>(f1b, f2T + (size_t)d * 384 * 1536, 384, 1536, ff_b2 + d * E_, ls2 + d * E_, h, nullptr, nullptr);
  }

  copy_out<<<(MROWS * E_ + 255) / 256, 256, 0, stream>>>(h, out);
}

// Round 4
// 2571.150 us; speedup vs baseline: 1.2007x; 1.0167x over previous
//
#include <hip/hip_runtime.h>
#include <math.h>

typedef __attribute__((ext_vector_type(8))) short short8;
typedef __attribute__((ext_vector_type(4))) float f32x4;
typedef unsigned short u16;

#define NTOK 841
#define GRID_H 29
#define E_ 384
#define NH_ 6
#define MROWS 13456
#define MP 13568
#define CM 5120
#define KB 128
#define KT7 7

__device__ __forceinline__ u16 f2bf(float f) {
  union { float f; unsigned int u; } c; c.f = f;
  unsigned int u = c.u;
  return (u16)((u + 0x7fffu + ((u >> 16) & 1u)) >> 16);
}

__device__ __forceinline__ float gelu_exact(float v) {
  return 0.5f * v * (1.f + erff(v * 0.70710678118654752440f));
}

__device__ __forceinline__ float fexp2(float x) {
  float r; asm("v_exp_f32 %0, %1" : "=v"(r) : "v"(x)); return r;
}

// byte offset in a [rows][128]-bf16 LDS tile (256B/row), 16B-chunk XOR swizzle
__device__ __forceinline__ int swz(int row, int col) {
  return row * 256 + ((((col >> 3) ^ (row & 7)) << 4) | ((col & 7) << 1));
}

// ---------------- transpose + fp32->bf16 convert: in [K][N] -> out [N][K] ----
__global__ __launch_bounds__(256) void transpose_conv(const float* __restrict__ in,
    u16* __restrict__ out, int K, int N) {
  __shared__ float tile[32][33];
  size_t zo = (size_t)blockIdx.z * K * N;
  const float* inp = in + zo;
  u16* outp = out + zo;
  int n0 = blockIdx.x * 32, k0 = blockIdx.y * 32;
  int tx = threadIdx.x & 31, ty = threadIdx.x >> 5;
  #pragma unroll
  for (int r = ty; r < 32; r += 8) tile[r][tx] = inp[(size_t)(k0 + r) * N + n0 + tx];
  __syncthreads();
  #pragma unroll
  for (int r = ty; r < 32; r += 8) outp[(size_t)(n0 + r) * K + k0 + tx] = f2bf(tile[tx][r]);
}

// ---------------- fused 5-shift patchify + LayerNorm(3840) -> bf16 ----------
__global__ __launch_bounds__(256) void patch_ln(const float* __restrict__ x,
    const float* __restrict__ g, const float* __restrict__ bsh, u16* __restrict__ out,
    int t0) {
  int t = t0 + blockIdx.x;
  int tid = threadIdx.x;
  u16* orow = out + (size_t)blockIdx.x * 3840;
  if (t >= MROWS) {
    #pragma unroll
    for (int j = 0; j < 15; ++j) orow[tid + j * 256] = 0;  // bf16 zero
    return;
  }
  int bimg = t / NTOK, n = t % NTOK;
  int gy = n / GRID_H, gx = n % GRID_H;
  float vals[15];
  float s1 = 0.f, s2 = 0.f;
  #pragma unroll
  for (int j = 0; j < 15; ++j) {
    int cout = tid + j * 256;
    int s = cout / 768, rem = cout % 768;
    int c = rem / 256, rem2 = rem % 256;
    int py = rem2 / 16, px = rem2 % 16;
    int dy = (s == 1 ? 8 : 0) - (s == 2 ? 8 : 0);
    int dx = (s == 3 ? 8 : 0) - (s == 4 ? 8 : 0);
    int Y = gy * 16 + py - dy;
    int X = gx * 16 + px - dx;
    float v = 0.f;
    if (Y >= 0 && Y < 464 && X >= 0 && X < 464)
      v = x[(((size_t)bimg * 3 + c) * 464 + Y) * 464 + X];
    vals[j] = v;
    s1 += v; s2 += v * v;
  }
  #pragma unroll
  for (int m = 1; m < 64; m <<= 1) { s1 += __shfl_xor(s1, m); s2 += __shfl_xor(s2, m); }
  __shared__ float ws1[4], ws2[4];
  int wid = tid >> 6;
  if ((tid & 63) == 0) { ws1[wid] = s1; ws2[wid] = s2; }
  __syncthreads();
  s1 = ws1[0] + ws1[1] + ws1[2] + ws1[3];
  s2 = ws2[0] + ws2[1] + ws2[2] + ws2[3];
  float mean = s1 * (1.f / 3840.f);
  float var = s2 * (1.f / 3840.f) - mean * mean;
  float rs = rsqrtf(var + 1e-5f);
  #pragma unroll
  for (int j = 0; j < 15; ++j) {
    int cout = tid + j * 256;
    orow[cout] = f2bf((vals[j] - mean) * rs * g[cout] + bsh[cout]);
  }
}

// ---------------- LayerNorm(384) fp32 -> bf16 --------------------------------
__global__ __launch_bounds__(256) void ln384(const float* __restrict__ h,
    const float* __restrict__ g, const float* __restrict__ bsh, u16* __restrict__ y) {
  int row = blockIdx.x * 4 + (threadIdx.x >> 6);
  int lane = threadIdx.x & 63;
  const float* hr = h + (size_t)row * E_;
  float v[6];
  float s1 = 0.f;
  #pragma unroll
  for (int j = 0; j < 6; ++j) { v[j] = hr[lane + j * 64]; s1 += v[j]; }
  #pragma unroll
  for (int m = 1; m < 64; m <<= 1) s1 += __shfl_xor(s1, m);
  float mean = s1 * (1.f / 384.f);
  float s2 = 0.f;
  #pragma unroll
  for (int j = 0; j < 6; ++j) { float d = v[j] - mean; s2 += d * d; }
  #pragma unroll
  for (int m = 1; m < 64; m <<= 1) s2 += __shfl_xor(s2, m);
  float rs = rsqrtf(s2 * (1.f / 384.f) + 1e-5f);
  u16* yr = y + (size_t)row * E_;
  #pragma unroll
  for (int j = 0; j < 6; ++j) {
    int c = lane + j * 64;
    yr[c] = f2bf((v[j] - mean) * rs * g[c] + bsh[c]);
  }
}

// ---------------- bf16 MFMA GEMM: C[M][N] = A[M][K] * BT[N][K]^T -------------
// EPI: 0 = bf16 out plain; 1 = bf16 out gelu(acc+bias); 2 = f32 out acc+bias;
//      3 = resid[m][n] += lscale[n]*(acc+bias[n])
template<int EPI>
__global__ __launch_bounds__(256) void gemm_bt(
    const u16* __restrict__ A, const u16* __restrict__ BT,
    int N, int K,
    const float* __restrict__ bias, const float* __restrict__ lscale,
    float* __restrict__ resid, u16* __restrict__ outb, float* __restrict__ outf) {
  __shared__ alignas(16) short As[128 * 64];
  __shared__ alignas(16) short Bs[128 * 64];
  // bijective XCD swizzle (m204): cluster consecutive work on one XCD
  const int gx = gridDim.x;
  const int nwg = gx * gridDim.y;
  int L = blockIdx.x + blockIdx.y * gx;
  int q8 = nwg >> 3, r8 = nwg & 7, xcd = L & 7, pos = L >> 3;
  int L2 = (xcd < r8 ? xcd * (q8 + 1) : r8 * (q8 + 1) + (xcd - r8) * q8) + pos;
  const int m0 = (L2 / gx) * 128, n0 = (L2 % gx) * 128;
  const int tid = threadIdx.x;
  const int lane = tid & 63, wid = tid >> 6;
  const int wm = wid >> 1, wn = wid & 1;
  f32x4 acc[4][4] = {};
  const int nkt = K >> 6;
  for (int kt = 0; kt < nkt; ++kt) {
    __syncthreads();
    const int k0 = kt * 64;
    #pragma unroll
    for (int i = 0; i < 4; ++i) {
      int chunk = i * 4 + wid;                 // 0..15, each = 512 elems (8 rows)
      int e = (chunk << 9) + (lane << 3);
      int row = e >> 6, col = e & 63;
      const u16* ga = A + (size_t)(m0 + row) * K + k0 + col;
      const u16* gb = BT + (size_t)(n0 + row) * K + k0 + col;
      __builtin_amdgcn_global_load_lds((const __attribute__((address_space(1))) void*)ga,
          (__attribute__((address_space(3))) void*)(As + (chunk << 9)), 16, 0, 0);
      __builtin_amdgcn_global_load_lds((const __attribute__((address_space(1))) void*)gb,
          (__attribute__((address_space(3))) void*)(Bs + (chunk << 9)), 16, 0, 0);
    }
    __syncthreads();
    #pragma unroll
    for (int kk = 0; kk < 2; ++kk) {
      short8 a[4], bfr[4];
      #pragma unroll
      for (int mi = 0; mi < 4; ++mi)
        a[mi] = *(const short8*)(As + (wm * 64 + mi * 16 + (lane & 15)) * 64 + kk * 32 + ((lane >> 4) << 3));
      #pragma unroll
      for (int nj = 0; nj < 4; ++nj)
        bfr[nj] = *(const short8*)(Bs + (wn * 64 + nj * 16 + (lane & 15)) * 64 + kk * 32 + ((lane >> 4) << 3));
      #pragma unroll
      for (int mi = 0; mi < 4; ++mi)
        #pragma unroll
        for (int nj = 0; nj < 4; ++nj)
          acc[mi][nj] = __builtin_amdgcn_mfma_f32_16x16x32_bf16(a[mi], bfr[nj], acc[mi][nj], 0, 0, 0);
    }
  }
  const int rrow = (lane >> 4) << 2;
  const int ccol = lane & 15;
  #pragma unroll
  for (int mi = 0; mi < 4; ++mi)
    #pragma unroll
    for (int nj = 0; nj < 4; ++nj) {
      int gn = n0 + wn * 64 + nj * 16 + ccol;
      #pragma unroll
      for (int r = 0; r < 4; ++r) {
        int gm = m0 + wm * 64 + mi * 16 + rrow + r;
        float v = acc[mi][nj][r];
        if (EPI == 0) {
          outb[(size_t)gm * N + gn] = f2bf(v);
        } else if (EPI == 1) {
          outb[(size_t)gm * N + gn] = f2bf(gelu_exact(v + bias[gn]));
        } else if (EPI == 2) {
          outf[(size_t)gm * N + gn] = v + bias[gn];
        } else {
          float* p = resid + (size_t)gm * N + gn;
          *p = *p + lscale[gn] * (v + bias[gn]);
        }
      }
    }
}

// ---------------- flash attention, deferred softmax, 32KB LDS ----------------
__global__ __launch_bounds__(256) void attn(const u16* __restrict__ qkv,
    const float* __restrict__ temp_d, const float* __restrict__ locw_d,
    u16* __restrict__ o) {
  // XCD swizzle: 1344 = 8 * 168; all 14 q-tiles of one (b,h) on one XCD
  int Lw = blockIdx.x + blockIdx.y * 14;
  int L2 = (Lw & 7) * 168 + (Lw >> 3);
  const int qt = L2 % 14, bh = L2 / 14;
  const int bimg = bh / NH_, hh = bh % NH_;
  const int tid = threadIdx.x, lane = tid & 63, w = tid >> 6;
  const int lg = lane >> 4, lc = lane & 15;
  const float LOG2E = 1.44269504088896f;
  const float scale = __expf(temp_d[hh]) * LOG2E;   // exp2-domain
  const float lw = locw_d[hh] * LOG2E;

  __shared__ alignas(16) char vt[64 * 256];       // V^T [hd][tok], swizzled
  __shared__ alignas(16) char pl[4][16 * 256];    // per-wave P [q][tok], swizzled

  // Q fragments (A-frag: row = lc, k = lg*8 + j)
  int qrow_local = qt * 64 + w * 16 + lc;
  int qrow_c = qrow_local < NTOK ? qrow_local : NTOK - 1;
  const u16* qptr = qkv + ((size_t)(bimg * NTOK + qrow_c)) * 1152 + hh * 64;
  short8 qf0 = *(const short8*)(qptr + (lg << 3));
  short8 qf1 = *(const short8*)(qptr + 32 + (lg << 3));

  float qy[4], qx[4];
  #pragma unroll
  for (int r = 0; r < 4; ++r) {
    int iq = qt * 64 + w * 16 + (lg << 2) + r;
    if (iq >= NTOK) iq = NTOK - 1;
    qy[r] = (float)(iq / GRID_H) * (1.f / 28.f);
    qx[r] = (float)(iq % GRID_H) * (1.f / 28.f);
  }

  f32x4 of[4] = {};
  float mrow[4], psum[4];
  #pragma unroll
  for (int r = 0; r < 4; ++r) { mrow[r] = -3e38f; psum[r] = 0.f; }

  // V staging: thread owns token-pair (2 toks) x 16 hd rows [hdb, hdb+16)
  const int vp = lane, hdb = w << 4;
  short8 vr0, vr1, vr2, vr3;
  auto vload = [&](int kt) {
    int t0 = kt * KB + 2 * vp;
    int r0 = t0 < NTOK ? t0 : NTOK - 1;
    int r1 = t0 + 1 < NTOK ? t0 + 1 : NTOK - 1;
    const u16* p0 = qkv + (size_t)(bimg * NTOK + r0) * 1152 + 768 + hh * 64 + hdb;
    const u16* p1 = qkv + (size_t)(bimg * NTOK + r1) * 1152 + 768 + hh * 64 + hdb;
    vr0 = *(const short8*)p0; vr1 = *(const short8*)(p0 + 8);
    vr2 = *(const short8*)p1; vr3 = *(const short8*)(p1 + 8);
  };
  auto vwrite = [&]() {
    #pragma unroll
    for (int j = 0; j < 8; ++j) {
      unsigned int u = (unsigned int)(unsigned short)vr0[j] |
                       ((unsigned int)(unsigned short)vr2[j] << 16);
      *(unsigned int*)(vt + swz(hdb + j, 2 * vp)) = u;
    }
    #pragma unroll
    for (int j = 0; j < 8; ++j) {
      unsigned int u = (unsigned int)(unsigned short)vr1[j] |
                       ((unsigned int)(unsigned short)vr3[j] << 16);
      *(unsigned int*)(vt + swz(hdb + 8 + j, 2 * vp)) = u;
    }
  };

  vload(0);
  vwrite();
  __syncthreads();

  for (int kt = 0; kt < KT7; ++kt) {
    // S = Q K^T : 8 nt of 16 tokens (K direct from global/L2)
    f32x4 sf[8];
    __builtin_amdgcn_s_setprio(1);
    #pragma unroll
    for (int nt = 0; nt < 8; ++nt) {
      int ktok = kt * KB + nt * 16 + lc;
      int kr = ktok < NTOK ? ktok : NTOK - 1;
      const u16* kp = qkv + (size_t)(bimg * NTOK + kr) * 1152 + 384 + hh * 64;
      short8 kf0 = *(const short8*)(kp + (lg << 3));
      short8 kf1 = *(const short8*)(kp + 32 + (lg << 3));
      f32x4 z = {0.f, 0.f, 0.f, 0.f};
      z = __builtin_amdgcn_mfma_f32_16x16x32_bf16(qf0, kf0, z, 0, 0, 0);
      z = __builtin_amdgcn_mfma_f32_16x16x32_bf16(qf1, kf1, z, 0, 0, 0);
      sf[nt] = z;
    }
    __builtin_amdgcn_s_setprio(0);

    if (kt + 1 < KT7) vload(kt + 1);   // issue next V loads early (T14)

    // logits in exp2 domain: scale*S + lw*loc, tail mask
    float pv[8][4];
    #pragma unroll
    for (int nt = 0; nt < 8; ++nt) {
      int j = kt * KB + nt * 16 + lc;
      bool valid = j < NTOK;
      unsigned jc = valid ? (unsigned)j : (NTOK - 1);
      float jy = (float)(jc / 29u) * (1.f / 28.f);
      float jx = (float)(jc % 29u) * (1.f / 28.f);
      #pragma unroll
      for (int r = 0; r < 4; ++r) {
        float dy = qy[r] - jy, dx = qx[r] - jx;
        float val = sf[nt][r] * scale - lw * 0.5f * (dy * dy + dx * dx);
        pv[nt][r] = valid ? val : -3e38f;
      }
    }

    // lane-local max per row slot
    float lm[4];
    #pragma unroll
    for (int r = 0; r < 4; ++r) {
      float t0 = fmaxf(pv[0][r], pv[1][r]);
      float t1 = fmaxf(pv[2][r], pv[3][r]);
      float t2 = fmaxf(pv[4][r], pv[5][r]);
      float t3 = fmaxf(pv[6][r], pv[7][r]);
      lm[r] = fmaxf(fmaxf(t0, t1), fmaxf(t2, t3));
    }
    // deferred-max: only reduce + rescale when some lane exceeds m+12 (exp2 units)
    bool trig = (lm[0] > mrow[0] + 12.f) | (lm[1] > mrow[1] + 12.f) |
                (lm[2] > mrow[2] + 12.f) | (lm[3] > mrow[3] + 12.f);
    if (__any(trig)) {
      #pragma unroll
      for (int r = 0; r < 4; ++r) {
        float tm = lm[r];
        #pragma unroll
        for (int m = 1; m < 16; m <<= 1) tm = fmaxf(tm, __shfl_xor(tm, m));
        float mnew = fmaxf(mrow[r], tm);
        float alpha = fexp2(mrow[r] - mnew);
        psum[r] *= alpha;
        of[0][r] *= alpha; of[1][r] *= alpha; of[2][r] *= alpha; of[3][r] *= alpha;
        mrow[r] = mnew;
      }
    }

    // exp2 + per-lane partial sum + P -> LDS (swizzled)
    char* plw = pl[w];
    #pragma unroll
    for (int nt = 0; nt < 8; ++nt)
      #pragma unroll
      for (int r = 0; r < 4; ++r) {
        float p = fexp2(pv[nt][r] - mrow[r]);
        psum[r] += p;
        *(u16*)(plw + swz((lg << 2) + r, nt * 16 + lc)) = f2bf(p);
      }
    asm volatile("s_waitcnt lgkmcnt(0)" ::: "memory");
    __builtin_amdgcn_sched_barrier(0);
    short8 pa[4];
    #pragma unroll
    for (int t = 0; t < 4; ++t)
      pa[t] = *(const short8*)(plw + swz(lc, t * 32 + (lg << 3)));

    // O += P V
    __builtin_amdgcn_s_setprio(1);
    #pragma unroll
    for (int n2 = 0; n2 < 4; ++n2) {
      f32x4 accv = of[n2];
      #pragma unroll
      for (int t = 0; t < 4; ++t) {
        short8 vf = *(const short8*)(vt + swz(n2 * 16 + lc, t * 32 + (lg << 3)));
        accv = __builtin_amdgcn_mfma_f32_16x16x32_bf16(pa[t], vf, accv, 0, 0, 0);
      }
      of[n2] = accv;
    }
    __builtin_amdgcn_s_setprio(0);

    if (kt + 1 < KT7) {
      __syncthreads();      // all PV reads of vt done
      vwrite();             // stage V_{kt+1}
      __syncthreads();      // vt ready
    }
  }

  // final: one cross-lane sum per row
  #pragma unroll
  for (int r = 0; r < 4; ++r) {
    float s = psum[r];
    #pragma unroll
    for (int m = 1; m < 16; m <<= 1) s += __shfl_xor(s, m);
    int iq = qt * 64 + w * 16 + (lg << 2) + r;
    if (iq < NTOK) {
      float rl = 1.f / s;
      #pragma unroll
      for (int n2 = 0; n2 < 4; ++n2)
        o[((size_t)(bimg * NTOK + iq)) * E_ + hh * 64 + n2 * 16 + lc] =
            f2bf(of[n2][r] * rl);
    }
  }
}

// ---------------- final copy h[0:13456] -> out -------------------------------
__global__ __launch_bounds__(256) void copy_out(const float* __restrict__ h, float* __restrict__ out) {
  size_t i = (size_t)blockIdx.x * 256 + threadIdx.x;
  if (i < (size_t)MROWS * E_) out[i] = h[i];
}

extern "C" void kernel_launch(void* const* d_in, const int* in_sizes, int n_in,
                              void* d_out, int out_size, void* d_ws, size_t ws_size,
                              hipStream_t stream) {
  const float* x      = (const float*)d_in[0];
  const float* tok_ng = (const float*)d_in[1];
  const float* tok_nb = (const float*)d_in[2];
  const float* tok_w1 = (const float*)d_in[3];
  const float* tok_b1 = (const float*)d_in[4];
  const float* tok_w2 = (const float*)d_in[5];
  const float* tok_b2 = (const float*)d_in[6];
  const float* ln1_g  = (const float*)d_in[7];
  const float* ln1_b  = (const float*)d_in[8];
  const float* w_qkv  = (const float*)d_in[9];
  const float* temp   = (const float*)d_in[10];
  const float* loc_w  = (const float*)d_in[11];
  const float* w_proj = (const float*)d_in[12];
  const float* b_proj = (const float*)d_in[13];
  const float* ls1    = (const float*)d_in[14];
  const float* ln2_g  = (const float*)d_in[15];
  const float* ln2_b  = (const float*)d_in[16];
  const float* ff_w1  = (const float*)d_in[17];
  const float* ff_b1  = (const float*)d_in[18];
  const float* ff_w2  = (const float*)d_in[19];
  const float* ff_b2  = (const float*)d_in[20];
  const float* ls2    = (const float*)d_in[21];
  float* out = (float*)d_out;

  char* ws = (char*)d_ws;
  size_t off = 0;
  auto alloc = [&](size_t bytes) -> void* {
    void* p = ws + off; off += (bytes + 255) & ~(size_t)255; return p;
  };
  // weights (persistent per launch)
  u16* w1T   = (u16*)alloc(768UL * 3840 * 2);
  u16* w2T   = (u16*)alloc(384UL * 768 * 2);
  u16* qkvT  = (u16*)alloc(8UL * 1152 * 384 * 2);
  u16* projT = (u16*)alloc(8UL * 384 * 384 * 2);
  u16* f1T   = (u16*)alloc(8UL * 1536 * 384 * 2);
  u16* f2T   = (u16*)alloc(8UL * 384 * 1536 * 2);
  // persistent activation
  float* h   = (float*)alloc((size_t)MP * 384 * 4);
  // regB: h1 (embed phase) OR y+ob (block phase)
  char* regB = (char*)alloc((size_t)MP * 768 * 2);
  u16* h1 = (u16*)regB;
  u16* y  = (u16*)regB;
  u16* ob = (u16*)(regB + (size_t)MP * 384 * 2);
  // regA: Xlnc (embed) OR qkvb (attn) OR f1b (ff)
  char* regA = (char*)alloc((size_t)MP * 1536 * 2);
  u16* Xlnc = (u16*)regA;   // CM*3840*2 = 39.3MB <= 41.7MB
  u16* qkvb = (u16*)regA;
  u16* f1b  = (u16*)regA;
  (void)in_sizes; (void)n_in; (void)out_size;

  if (off > ws_size) return;  // diagnostic: leaves d_out untouched -> absmax ~2.5

  // weight transposes (fp32 [K][N] -> bf16 [N][K])
  transpose_conv<<<dim3(24, 120, 1), 256, 0, stream>>>(tok_w1, w1T, 3840, 768);
  transpose_conv<<<dim3(12, 24, 1), 256, 0, stream>>>(tok_w2, w2T, 768, 384);
  transpose_conv<<<dim3(36, 12, 8), 256, 0, stream>>>(w_qkv, qkvT, 384, 1152);
  transpose_conv<<<dim3(12, 12, 8), 256, 0, stream>>>(w_proj, projT, 384, 384);
  transpose_conv<<<dim3(48, 12, 8), 256, 0, stream>>>(ff_w1, f1T, 384, 1536);
  transpose_conv<<<dim3(12, 48, 8), 256, 0, stream>>>(ff_w2, f2T, 1536, 384);

  // patch embed + LN(3840) + first GEMM, chunked through Xlnc
  for (int m = 0; m < MP; m += CM) {
    int rows = MP - m; if (rows > CM) rows = CM;
    patch_ln<<<rows, 256, 0, stream>>>(x, tok_ng, tok_nb, Xlnc, m);
    gemm_bt<1><<<dim3(6, rows / 128), 256, 0, stream>>>(Xlnc, w1T, 768, 3840,
        tok_b1, nullptr, nullptr, h1 + (size_t)m * 768, nullptr);
  }
  gemm_bt<2><<<dim3(3, MP / 128), 256, 0, stream>>>(h1, w2T, 384, 768, tok_b2, nullptr, nullptr, nullptr, h);

  for (int d = 0; d < 8; ++d) {
    ln384<<<MP / 4, 256, 0, stream>>>(h, ln1_g + d * E_, ln1_b + d * E_, y);
    gemm_bt<0><<<dim3(9, MP / 128), 256, 0, stream>>>(y, qkvT + (size_t)d * 1152 * 384, 1152, 384, nullptr, nullptr, nullptr, qkvb, nullptr);
    attn<<<dim3(14, 96), 256, 0, stream>>>(qkvb, temp + d * NH_, loc_w + d * NH_, ob);
    gemm_bt<3><<<dim3(3, MP / 128), 256, 0, stream>>>(ob, projT + (size_t)d * 384 * 384, 384, 384, b_proj + d * E_, ls1 + d * E_, h, nullptr, nullptr);
    ln384<<<MP / 4, 256, 0, stream>>>(h, ln2_g + d * E_, ln2_b + d * E_, y);
    gemm_bt<1><<<dim3(12, MP / 128), 256, 0, stream>>>(y, f1T + (size_t)d * 1536 * 384, 1536, 384, ff_b1 + d * 1536, nullptr, nullptr, f1b, nullptr);
    gemm_bt<3><<<dim3(3, MP / 128), 256, 0, stream>>>(f1b, f2T + (size_t)d * 384 * 1536, 384, 1536, ff_b2 + d * E_, ls2 + d * E_, h, nullptr, nullptr);
  }

  copy_out<<<(MROWS * E_ + 255) / 256, 256, 0, stream>>>(h, out);
}

// Round 5
// 2518.500 us; speedup vs baseline: 1.2258x; 1.0209x over previous
//
#include <hip/hip_runtime.h>
#include <math.h>

typedef __attribute__((ext_vector_type(8))) short short8;
typedef __attribute__((ext_vector_type(4))) float f32x4;
typedef unsigned short u16;

#define NTOK 841
#define GRID_H 29
#define E_ 384
#define NH_ 6
#define MROWS 13456
#define MP 13568
#define CM 5120
#define KB 128
#define KT7 7

__device__ __forceinline__ u16 f2bf(float f) {
  union { float f; unsigned int u; } c; c.f = f;
  unsigned int u = c.u;
  return (u16)((u + 0x7fffu + ((u >> 16) & 1u)) >> 16);
}

__device__ __forceinline__ float gelu_exact(float v) {
  return 0.5f * v * (1.f + erff(v * 0.70710678118654752440f));
}

__device__ __forceinline__ float fexp2(float x) {
  float r; asm("v_exp_f32 %0, %1" : "=v"(r) : "v"(x)); return r;
}

// byte offset in a [rows][128]-bf16 LDS tile (256B/row), 16B-chunk XOR swizzle
__device__ __forceinline__ int swz(int row, int col) {
  return row * 256 + ((((col >> 3) ^ (row & 7)) << 4) | ((col & 7) << 1));
}

// ---------------- distance-bias table: d2t[i][j] = -0.5*((yi-yj)^2+(xi-xj)^2)
__global__ __launch_bounds__(256) void d2tab_k(float* __restrict__ t) {
  int idx = blockIdx.x * 256 + threadIdx.x;
  if (idx >= 896 * 896) return;
  unsigned i = (unsigned)idx / 896u, j = (unsigned)idx % 896u;
  unsigned ic = i < NTOK ? i : NTOK - 1, jc = j < NTOK ? j : NTOK - 1;
  float qy = (float)(ic / 29u) * (1.f / 28.f), qx = (float)(ic % 29u) * (1.f / 28.f);
  float jy = (float)(jc / 29u) * (1.f / 28.f), jx = (float)(jc % 29u) * (1.f / 28.f);
  float dy = qy - jy, dx = qx - jx;
  t[idx] = -0.5f * (dy * dy + dx * dx);
}

// ---------------- transpose + fp32->bf16 convert: in [K][N] -> out [N][K] ----
__global__ __launch_bounds__(256) void transpose_conv(const float* __restrict__ in,
    u16* __restrict__ out, int K, int N) {
  __shared__ float tile[32][33];
  size_t zo = (size_t)blockIdx.z * K * N;
  const float* inp = in + zo;
  u16* outp = out + zo;
  int n0 = blockIdx.x * 32, k0 = blockIdx.y * 32;
  int tx = threadIdx.x & 31, ty = threadIdx.x >> 5;
  #pragma unroll
  for (int r = ty; r < 32; r += 8) tile[r][tx] = inp[(size_t)(k0 + r) * N + n0 + tx];
  __syncthreads();
  #pragma unroll
  for (int r = ty; r < 32; r += 8) outp[(size_t)(n0 + r) * K + k0 + tx] = f2bf(tile[tx][r]);
}

// ---------------- fused 5-shift patchify + LayerNorm(3840) -> bf16 ----------
__global__ __launch_bounds__(256) void patch_ln(const float* __restrict__ x,
    const float* __restrict__ g, const float* __restrict__ bsh, u16* __restrict__ out,
    int t0) {
  int t = t0 + blockIdx.x;
  int tid = threadIdx.x;
  u16* orow = out + (size_t)blockIdx.x * 3840;
  if (t >= MROWS) {
    #pragma unroll
    for (int j = 0; j < 15; ++j) orow[tid + j * 256] = 0;  // bf16 zero
    return;
  }
  int bimg = t / NTOK, n = t % NTOK;
  int gy = n / GRID_H, gx = n % GRID_H;
  float vals[15];
  float s1 = 0.f, s2 = 0.f;
  #pragma unroll
  for (int j = 0; j < 15; ++j) {
    int cout = tid + j * 256;
    int s = cout / 768, rem = cout % 768;
    int c = rem / 256, rem2 = rem % 256;
    int py = rem2 / 16, px = rem2 % 16;
    int dy = (s == 1 ? 8 : 0) - (s == 2 ? 8 : 0);
    int dx = (s == 3 ? 8 : 0) - (s == 4 ? 8 : 0);
    int Y = gy * 16 + py - dy;
    int X = gx * 16 + px - dx;
    float v = 0.f;
    if (Y >= 0 && Y < 464 && X >= 0 && X < 464)
      v = x[(((size_t)bimg * 3 + c) * 464 + Y) * 464 + X];
    vals[j] = v;
    s1 += v; s2 += v * v;
  }
  #pragma unroll
  for (int m = 1; m < 64; m <<= 1) { s1 += __shfl_xor(s1, m); s2 += __shfl_xor(s2, m); }
  __shared__ float ws1[4], ws2[4];
  int wid = tid >> 6;
  if ((tid & 63) == 0) { ws1[wid] = s1; ws2[wid] = s2; }
  __syncthreads();
  s1 = ws1[0] + ws1[1] + ws1[2] + ws1[3];
  s2 = ws2[0] + ws2[1] + ws2[2] + ws2[3];
  float mean = s1 * (1.f / 3840.f);
  float var = s2 * (1.f / 3840.f) - mean * mean;
  float rs = rsqrtf(var + 1e-5f);
  #pragma unroll
  for (int j = 0; j < 15; ++j) {
    int cout = tid + j * 256;
    orow[cout] = f2bf((vals[j] - mean) * rs * g[cout] + bsh[cout]);
  }
}

// ---------------- LayerNorm(384) fp32 -> bf16 --------------------------------
__global__ __launch_bounds__(256) void ln384(const float* __restrict__ h,
    const float* __restrict__ g, const float* __restrict__ bsh, u16* __restrict__ y) {
  int row = blockIdx.x * 4 + (threadIdx.x >> 6);
  int lane = threadIdx.x & 63;
  const float* hr = h + (size_t)row * E_;
  float v[6];
  float s1 = 0.f;
  #pragma unroll
  for (int j = 0; j < 6; ++j) { v[j] = hr[lane + j * 64]; s1 += v[j]; }
  #pragma unroll
  for (int m = 1; m < 64; m <<= 1) s1 += __shfl_xor(s1, m);
  float mean = s1 * (1.f / 384.f);
  float s2 = 0.f;
  #pragma unroll
  for (int j = 0; j < 6; ++j) { float d = v[j] - mean; s2 += d * d; }
  #pragma unroll
  for (int m = 1; m < 64; m <<= 1) s2 += __shfl_xor(s2, m);
  float rs = rsqrtf(s2 * (1.f / 384.f) + 1e-5f);
  u16* yr = y + (size_t)row * E_;
  #pragma unroll
  for (int j = 0; j < 6; ++j) {
    int c = lane + j * 64;
    yr[c] = f2bf((v[j] - mean) * rs * g[c] + bsh[c]);
  }
}

// ---------------- bf16 MFMA GEMM: C[M][N] = A[M][K] * BT[N][K]^T -------------
// EPI: 0 = bf16 out plain; 1 = bf16 out gelu(acc+bias); 2 = f32 out acc+bias;
//      3 = resid[m][n] += lscale[n]*(acc+bias[n])
// TM: 128 or 64 (row-tile height)
template<int EPI, int TM>
__global__ __launch_bounds__(256) void gemm_bt(
    const u16* __restrict__ A, const u16* __restrict__ BT,
    int N, int K,
    const float* __restrict__ bias, const float* __restrict__ lscale,
    float* __restrict__ resid, u16* __restrict__ outb, float* __restrict__ outf) {
  constexpr int MI = TM / 32;   // acc rows per wave
  __shared__ alignas(16) short As[TM * 64];
  __shared__ alignas(16) short Bs[128 * 64];
  // bijective XCD swizzle (m204): cluster consecutive work on one XCD
  const int gx = gridDim.x;
  const int nwg = gx * gridDim.y;
  int L = blockIdx.x + blockIdx.y * gx;
  int q8 = nwg >> 3, r8 = nwg & 7, xcd = L & 7, pos = L >> 3;
  int L2 = (xcd < r8 ? xcd * (q8 + 1) : r8 * (q8 + 1) + (xcd - r8) * q8) + pos;
  const int m0 = (L2 / gx) * TM, n0 = (L2 % gx) * 128;
  const int tid = threadIdx.x;
  const int lane = tid & 63, wid = tid >> 6;
  const int wm = wid >> 1, wn = wid & 1;
  f32x4 acc[MI][4] = {};
  const int nkt = K >> 6;
  for (int kt = 0; kt < nkt; ++kt) {
    __syncthreads();
    const int k0 = kt * 64;
    #pragma unroll
    for (int i = 0; i < TM / 32; ++i) {
      int chunk = i * 4 + wid;                 // each = 512 elems (8 rows)
      int e = (chunk << 9) + (lane << 3);
      int row = e >> 6, col = e & 63;
      const u16* ga = A + (size_t)(m0 + row) * K + k0 + col;
      __builtin_amdgcn_global_load_lds((const __attribute__((address_space(1))) void*)ga,
          (__attribute__((address_space(3))) void*)(As + (chunk << 9)), 16, 0, 0);
    }
    #pragma unroll
    for (int i = 0; i < 4; ++i) {
      int chunk = i * 4 + wid;
      int e = (chunk << 9) + (lane << 3);
      int row = e >> 6, col = e & 63;
      const u16* gb = BT + (size_t)(n0 + row) * K + k0 + col;
      __builtin_amdgcn_global_load_lds((const __attribute__((address_space(1))) void*)gb,
          (__attribute__((address_space(3))) void*)(Bs + (chunk << 9)), 16, 0, 0);
    }
    __syncthreads();
    #pragma unroll
    for (int kk = 0; kk < 2; ++kk) {
      short8 a[MI], bfr[4];
      #pragma unroll
      for (int mi = 0; mi < MI; ++mi)
        a[mi] = *(const short8*)(As + (wm * (TM / 2) + mi * 16 + (lane & 15)) * 64 + kk * 32 + ((lane >> 4) << 3));
      #pragma unroll
      for (int nj = 0; nj < 4; ++nj)
        bfr[nj] = *(const short8*)(Bs + (wn * 64 + nj * 16 + (lane & 15)) * 64 + kk * 32 + ((lane >> 4) << 3));
      #pragma unroll
      for (int mi = 0; mi < MI; ++mi)
        #pragma unroll
        for (int nj = 0; nj < 4; ++nj)
          acc[mi][nj] = __builtin_amdgcn_mfma_f32_16x16x32_bf16(a[mi], bfr[nj], acc[mi][nj], 0, 0, 0);
    }
  }
  const int rrow = (lane >> 4) << 2;
  const int ccol = lane & 15;
  #pragma unroll
  for (int mi = 0; mi < MI; ++mi)
    #pragma unroll
    for (int nj = 0; nj < 4; ++nj) {
      int gn = n0 + wn * 64 + nj * 16 + ccol;
      #pragma unroll
      for (int r = 0; r < 4; ++r) {
        int gm = m0 + wm * (TM / 2) + mi * 16 + rrow + r;
        float v = acc[mi][nj][r];
        if (EPI == 0) {
          outb[(size_t)gm * N + gn] = f2bf(v);
        } else if (EPI == 1) {
          outb[(size_t)gm * N + gn] = f2bf(gelu_exact(v + bias[gn]));
        } else if (EPI == 2) {
          outf[(size_t)gm * N + gn] = v + bias[gn];
        } else {
          float* p = resid + (size_t)gm * N + gn;
          *p = *p + lscale[gn] * (v + bias[gn]);
        }
      }
    }
}

// ---------------- flash attention: bias table, clamp-free, deferred softmax --
__global__ __launch_bounds__(256) void attn(const u16* __restrict__ qkv,
    const float* __restrict__ temp_d, const float* __restrict__ locw_d,
    const float* __restrict__ d2t, u16* __restrict__ o) {
  // XCD swizzle: 1344 = 8 * 168; all 14 q-tiles of one (b,h) on one XCD
  int Lw = blockIdx.x + blockIdx.y * 14;
  int L2 = (Lw & 7) * 168 + (Lw >> 3);
  const int qt = L2 % 14, bh = L2 / 14;
  const int bimg = bh / NH_, hh = bh % NH_;
  const int tid = threadIdx.x, lane = tid & 63, w = tid >> 6;
  const int lg = lane >> 4, lc = lane & 15;
  const float LOG2E = 1.44269504088896f;
  const float scale = __expf(temp_d[hh]) * LOG2E;   // exp2-domain
  const float lw2 = locw_d[hh] * LOG2E;

  __shared__ alignas(16) char vt[64 * 256];       // V^T [hd][tok], swizzled
  __shared__ alignas(16) char pl[4][16 * 256];    // per-wave P [q][tok], swizzled

  const u16* base = qkv + (size_t)(bimg * NTOK) * 1152;

  // Q fragments (A-frag: row = lc, k = lg*8 + j); rows ≤895 in-bounds, unclamped
  const u16* qptr = base + (size_t)(qt * 64 + w * 16 + lc) * 1152 + hh * 64 + (lg << 3);
  short8 qf0 = *(const short8*)(qptr);
  short8 qf1 = *(const short8*)(qptr + 32);

  // bias row pointers (rows ≤895 < 896, table handles q-index clamping)
  const float* bp[4];
  #pragma unroll
  for (int r = 0; r < 4; ++r)
    bp[r] = d2t + (size_t)(qt * 64 + w * 16 + (lg << 2) + r) * 896;

  f32x4 of[4] = {};
  float mrow[4], psum[4];
  #pragma unroll
  for (int r = 0; r < 4; ++r) { mrow[r] = -3e38f; psum[r] = 0.f; }

  // V staging: thread owns token-pair (2 toks) x 16 hd rows [hdb, hdb+16)
  const int vp = lane, hdb = w << 4;
  short8 vr0, vr1, vr2, vr3;
  auto vload = [&](int kt) {
    const u16* p0 = base + (size_t)(kt * KB + 2 * vp) * 1152 + 768 + hh * 64 + hdb;
    vr0 = *(const short8*)p0;          vr1 = *(const short8*)(p0 + 8);
    vr2 = *(const short8*)(p0 + 1152); vr3 = *(const short8*)(p0 + 1160);
  };
  auto vwrite = [&]() {
    #pragma unroll
    for (int j = 0; j < 8; ++j) {
      unsigned int u = (unsigned int)(unsigned short)vr0[j] |
                       ((unsigned int)(unsigned short)vr2[j] << 16);
      *(unsigned int*)(vt + swz(hdb + j, 2 * vp)) = u;
    }
    #pragma unroll
    for (int j = 0; j < 8; ++j) {
      unsigned int u = (unsigned int)(unsigned short)vr1[j] |
                       ((unsigned int)(unsigned short)vr3[j] << 16);
      *(unsigned int*)(vt + swz(hdb + 8 + j, 2 * vp)) = u;
    }
  };

  vload(0);
  vwrite();
  __syncthreads();

  for (int kt = 0; kt < KT7; ++kt) {
    // S = Q K^T : 8 nt of 16 tokens (K direct from global/L2, no clamps)
    f32x4 sf[8];
    const u16* kl = base + (size_t)(kt * KB + lc) * 1152 + 384 + hh * 64 + (lg << 3);
    __builtin_amdgcn_s_setprio(1);
    #pragma unroll
    for (int nt = 0; nt < 8; ++nt) {
      const u16* kp = kl + nt * 16 * 1152;
      short8 kf0 = *(const short8*)(kp);
      short8 kf1 = *(const short8*)(kp + 32);
      f32x4 z = {0.f, 0.f, 0.f, 0.f};
      z = __builtin_amdgcn_mfma_f32_16x16x32_bf16(qf0, kf0, z, 0, 0, 0);
      z = __builtin_amdgcn_mfma_f32_16x16x32_bf16(qf1, kf1, z, 0, 0, 0);
      sf[nt] = z;
    }
    __builtin_amdgcn_s_setprio(0);

    if (kt + 1 < KT7) vload(kt + 1);   // issue next V loads early (T14)

    // logits in-place: sf = scale*S + lw2*bias (table), tail mask
    #pragma unroll
    for (int r = 0; r < 4; ++r) {
      const float* bc = bp[r] + kt * KB + lc;
      #pragma unroll
      for (int nt = 0; nt < 8; ++nt) {
        float val = sf[nt][r] * scale + lw2 * bc[nt * 16];
        sf[nt][r] = (kt * KB + nt * 16 + lc < NTOK) ? val : -3e38f;
      }
    }

    // lane-local max per row slot
    float lm[4];
    #pragma unroll
    for (int r = 0; r < 4; ++r) {
      float t0 = fmaxf(sf[0][r], sf[1][r]);
      float t1 = fmaxf(sf[2][r], sf[3][r]);
      float t2 = fmaxf(sf[4][r], sf[5][r]);
      float t3 = fmaxf(sf[6][r], sf[7][r]);
      lm[r] = fmaxf(fmaxf(t0, t1), fmaxf(t2, t3));
    }
    // deferred-max: only reduce + rescale when some lane exceeds m+12 (exp2 units)
    bool trig = (lm[0] > mrow[0] + 12.f) | (lm[1] > mrow[1] + 12.f) |
                (lm[2] > mrow[2] + 12.f) | (lm[3] > mrow[3] + 12.f);
    if (__any(trig)) {
      #pragma unroll
      for (int r = 0; r < 4; ++r) {
        float tm = lm[r];
        #pragma unroll
        for (int m = 1; m < 16; m <<= 1) tm = fmaxf(tm, __shfl_xor(tm, m));
        float mnew = fmaxf(mrow[r], tm);
        float alpha = fexp2(mrow[r] - mnew);
        psum[r] *= alpha;
        of[0][r] *= alpha; of[1][r] *= alpha; of[2][r] *= alpha; of[3][r] *= alpha;
        mrow[r] = mnew;
      }
    }

    // exp2 + per-lane partial sum + P -> LDS (swizzled)
    char* plw = pl[w];
    #pragma unroll
    for (int nt = 0; nt < 8; ++nt)
      #pragma unroll
      for (int r = 0; r < 4; ++r) {
        float p = fexp2(sf[nt][r] - mrow[r]);
        psum[r] += p;
        *(u16*)(plw + swz((lg << 2) + r, nt * 16 + lc)) = f2bf(p);
      }
    asm volatile("s_waitcnt lgkmcnt(0)" ::: "memory");
    __builtin_amdgcn_sched_barrier(0);
    short8 pa[4];
    #pragma unroll
    for (int t = 0; t < 4; ++t)
      pa[t] = *(const short8*)(plw + swz(lc, t * 32 + (lg << 3)));

    // O += P V
    __builtin_amdgcn_s_setprio(1);
    #pragma unroll
    for (int n2 = 0; n2 < 4; ++n2) {
      f32x4 accv = of[n2];
      #pragma unroll
      for (int t = 0; t < 4; ++t) {
        short8 vf = *(const short8*)(vt + swz(n2 * 16 + lc, t * 32 + (lg << 3)));
        accv = __builtin_amdgcn_mfma_f32_16x16x32_bf16(pa[t], vf, accv, 0, 0, 0);
      }
      of[n2] = accv;
    }
    __builtin_amdgcn_s_setprio(0);

    if (kt + 1 < KT7) {
      __syncthreads();      // all PV reads of vt done
      vwrite();             // stage V_{kt+1}
      __syncthreads();      // vt ready
    }
  }

  // final: one cross-lane sum per row
  #pragma unroll
  for (int r = 0; r < 4; ++r) {
    float s = psum[r];
    #pragma unroll
    for (int m = 1; m < 16; m <<= 1) s += __shfl_xor(s, m);
    int iq = qt * 64 + w * 16 + (lg << 2) + r;
    if (iq < NTOK) {
      float rl = 1.f / s;
      #pragma unroll
      for (int n2 = 0; n2 < 4; ++n2)
        o[((size_t)(bimg * NTOK + iq)) * E_ + hh * 64 + n2 * 16 + lc] =
            f2bf(of[n2][r] * rl);
    }
  }
}

// ---------------- final copy h[0:13456] -> out -------------------------------
__global__ __launch_bounds__(256) void copy_out(const float* __restrict__ h, float* __restrict__ out) {
  size_t i = (size_t)blockIdx.x * 256 + threadIdx.x;
  if (i < (size_t)MROWS * E_) out[i] = h[i];
}

extern "C" void kernel_launch(void* const* d_in, const int* in_sizes, int n_in,
                              void* d_out, int out_size, void* d_ws, size_t ws_size,
                              hipStream_t stream) {
  const float* x      = (const float*)d_in[0];
  const float* tok_ng = (const float*)d_in[1];
  const float* tok_nb = (const float*)d_in[2];
  const float* tok_w1 = (const float*)d_in[3];
  const float* tok_b1 = (const float*)d_in[4];
  const float* tok_w2 = (const float*)d_in[5];
  const float* tok_b2 = (const float*)d_in[6];
  const float* ln1_g  = (const float*)d_in[7];
  const float* ln1_b  = (const float*)d_in[8];
  const float* w_qkv  = (const float*)d_in[9];
  const float* temp   = (const float*)d_in[10];
  const float* loc_w  = (const float*)d_in[11];
  const float* w_proj = (const float*)d_in[12];
  const float* b_proj = (const float*)d_in[13];
  const float* ls1    = (const float*)d_in[14];
  const float* ln2_g  = (const float*)d_in[15];
  const float* ln2_b  = (const float*)d_in[16];
  const float* ff_w1  = (const float*)d_in[17];
  const float* ff_b1  = (const float*)d_in[18];
  const float* ff_w2  = (const float*)d_in[19];
  const float* ff_b2  = (const float*)d_in[20];
  const float* ls2    = (const float*)d_in[21];
  float* out = (float*)d_out;

  char* ws = (char*)d_ws;
  size_t off = 0;
  auto alloc = [&](size_t bytes) -> void* {
    void* p = ws + off; off += (bytes + 255) & ~(size_t)255; return p;
  };
  // weights + tables (persistent per launch)
  u16* w1T   = (u16*)alloc(768UL * 3840 * 2);
  u16* w2T   = (u16*)alloc(384UL * 768 * 2);
  u16* qkvT  = (u16*)alloc(8UL * 1152 * 384 * 2);
  u16* projT = (u16*)alloc(8UL * 384 * 384 * 2);
  u16* f1T   = (u16*)alloc(8UL * 1536 * 384 * 2);
  u16* f2T   = (u16*)alloc(8UL * 384 * 1536 * 2);
  float* d2t = (float*)alloc(896UL * 896 * 4);
  // persistent activation
  float* h   = (float*)alloc((size_t)MP * 384 * 4);
  // regB: h1 (embed phase) OR y+ob (block phase)
  char* regB = (char*)alloc((size_t)MP * 768 * 2);
  u16* h1 = (u16*)regB;
  u16* y  = (u16*)regB;
  u16* ob = (u16*)(regB + (size_t)MP * 384 * 2);
  // regA: Xlnc (embed) OR qkvb (attn) OR f1b (ff)
  char* regA = (char*)alloc((size_t)MP * 1536 * 2);
  u16* Xlnc = (u16*)regA;   // CM*3840*2 = 39.3MB <= 41.7MB
  u16* qkvb = (u16*)regA;
  u16* f1b  = (u16*)regA;
  (void)in_sizes; (void)n_in; (void)out_size;

  if (off > ws_size) return;  // diagnostic: leaves d_out untouched -> absmax ~2.5

  // tables + weight transposes (fp32 [K][N] -> bf16 [N][K])
  d2tab_k<<<(896 * 896 + 255) / 256, 256, 0, stream>>>(d2t);
  transpose_conv<<<dim3(24, 120, 1), 256, 0, stream>>>(tok_w1, w1T, 3840, 768);
  transpose_conv<<<dim3(12, 24, 1), 256, 0, stream>>>(tok_w2, w2T, 768, 384);
  transpose_conv<<<dim3(36, 12, 8), 256, 0, stream>>>(w_qkv, qkvT, 384, 1152);
  transpose_conv<<<dim3(12, 12, 8), 256, 0, stream>>>(w_proj, projT, 384, 384);
  transpose_conv<<<dim3(48, 12, 8), 256, 0, stream>>>(ff_w1, f1T, 384, 1536);
  transpose_conv<<<dim3(12, 48, 8), 256, 0, stream>>>(ff_w2, f2T, 1536, 384);

  // patch embed + LN(3840) + first GEMM, chunked through Xlnc
  for (int m = 0; m < MP; m += CM) {
    int rows = MP - m; if (rows > CM) rows = CM;
    patch_ln<<<rows, 256, 0, stream>>>(x, tok_ng, tok_nb, Xlnc, m);
    gemm_bt<1, 128><<<dim3(6, rows / 128), 256, 0, stream>>>(Xlnc, w1T, 768, 3840,
        tok_b1, nullptr, nullptr, h1 + (size_t)m * 768, nullptr);
  }
  gemm_bt<2, 64><<<dim3(3, MP / 64), 256, 0, stream>>>(h1, w2T, 384, 768, tok_b2, nullptr, nullptr, nullptr, h);

  for (int d = 0; d < 8; ++d) {
    ln384<<<MP / 4, 256, 0, stream>>>(h, ln1_g + d * E_, ln1_b + d * E_, y);
    gemm_bt<0, 128><<<dim3(9, MP / 128), 256, 0, stream>>>(y, qkvT + (size_t)d * 1152 * 384, 1152, 384, nullptr, nullptr, nullptr, qkvb, nullptr);
    attn<<<dim3(14, 96), 256, 0, stream>>>(qkvb, temp + d * NH_, loc_w + d * NH_, d2t, ob);
    gemm_bt<3, 64><<<dim3(3, MP / 64), 256, 0, stream>>>(ob, projT + (size_t)d * 384 * 384, 384, 384, b_proj + d * E_, ls1 + d * E_, h, nullptr, nullptr);
    ln384<<<MP / 4, 256, 0, stream>>>(h, ln2_g + d * E_, ln2_b + d * E_, y);
    gemm_bt<1, 128><<<dim3(12, MP / 128), 256, 0, stream>>>(y, f1T + (size_t)d * 1536 * 384, 1536, 384, ff_b1 + d * 1536, nullptr, nullptr, f1b, nullptr);
    gemm_bt<3, 64><<<dim3(3, MP / 64), 256, 0, stream>>>(f1b, f2T + (size_t)d * 384 * 1536, 384, 1536, ff_b2 + d * E_, ls2 + d * E_, h, nullptr, nullptr);
  }

  copy_out<<<(MROWS * E_ + 255) / 256, 256, 0, stream>>>(h, out);
}